// Round 1
// baseline (385.710 us; speedup 1.0000x reference)
//
#include <hip/hip_runtime.h>

#define RR 8
#define TILE 32
#define EXT (TILE + 2 * RR)   // 48

// Kernel 1: per low-res pixel compute A = cov/(var+eps), b = mean_y - A*mean_x
// using clamped 17x17 box sums. Zero-pad out-of-bounds (equivalent to clamped
// window since OOB contributes 0); normalizer N computed analytically.
__global__ __launch_bounds__(1024) void k_ab(
    const float* __restrict__ lrx, const float* __restrict__ lry,
    float* __restrict__ Aout, float* __restrict__ Bout, int H, int W) {
  __shared__ float sx[EXT][EXT];
  __shared__ float sy[EXT][EXT];
  __shared__ float hx[EXT][TILE];
  __shared__ float hy[EXT][TILE];
  __shared__ float hxy[EXT][TILE];
  __shared__ float hxx[EXT][TILE];

  const int bc = blockIdx.z;
  const size_t plane = (size_t)bc * H * W;
  const float* __restrict__ px = lrx + plane;
  const float* __restrict__ py = lry + plane;
  const int tx0 = blockIdx.x * TILE;
  const int ty0 = blockIdx.y * TILE;
  const int tid = threadIdx.y * TILE + threadIdx.x;

  // Stage 48x48 region (zero outside image bounds)
  for (int i = tid; i < EXT * EXT; i += TILE * TILE) {
    int r = i / EXT, c = i % EXT;
    int gy = ty0 + r - RR, gx = tx0 + c - RR;
    float vx = 0.f, vy = 0.f;
    if (gy >= 0 && gy < H && gx >= 0 && gx < W) {
      size_t o = (size_t)gy * W + gx;
      vx = px[o];
      vy = py[o];
    }
    sx[r][c] = vx;
    sy[r][c] = vy;
  }
  __syncthreads();

  // Horizontal 17-tap sums: EXT rows x TILE cols, 4 quantities
  for (int i = tid; i < EXT * TILE; i += TILE * TILE) {
    int r = i / TILE, c = i % TILE;
    float ax = 0.f, ay = 0.f, axy = 0.f, axx = 0.f;
#pragma unroll
    for (int d = 0; d <= 2 * RR; ++d) {
      float vx = sx[r][c + d];
      float vy = sy[r][c + d];
      ax += vx;
      ay += vy;
      axy += vx * vy;
      axx += vx * vx;
    }
    hx[r][c] = ax;
    hy[r][c] = ay;
    hxy[r][c] = axy;
    hxx[r][c] = axx;
  }
  __syncthreads();

  // Vertical 17-tap + finalize
  const int c = threadIdx.x, r = threadIdx.y;
  float sX = 0.f, sY = 0.f, sXY = 0.f, sXX = 0.f;
#pragma unroll
  for (int d = 0; d <= 2 * RR; ++d) {
    sX += hx[r + d][c];
    sY += hy[r + d][c];
    sXY += hxy[r + d][c];
    sXX += hxx[r + d][c];
  }
  const int gy = ty0 + r, gx = tx0 + c;
  if (gy < H && gx < W) {
    int ny = min(gy + RR, H - 1) - max(gy - RR, 0) + 1;
    int nx = min(gx + RR, W - 1) - max(gx - RR, 0) + 1;
    float inv = 1.f / (float)(nx * ny);
    float mx = sX * inv;
    float my = sY * inv;
    float cov = sXY * inv - mx * my;
    float var = sXX * inv - mx * mx;
    float a = cov / (var + 1e-8f);
    float bv = my - a * mx;
    size_t o = plane + (size_t)gy * W + gx;
    Aout[o] = a;
    Bout[o] = bv;
  }
}

// Kernel 2: bilinear (align_corners) upsample of A,b fused with out = A*hr + b.
// One float4 of HR pixels per thread.
__global__ __launch_bounds__(256) void k_out(
    const float* __restrict__ A, const float* __restrict__ Bb,
    const float* __restrict__ hr, float* __restrict__ out,
    int hl, int wl, int Hh, int Wh) {
  const int xq = blockIdx.x * blockDim.x + threadIdx.x;  // float4 column
  const int y = blockIdx.y;
  const int bc = blockIdx.z;

  const float scy = (float)(hl - 1) / (float)(Hh - 1);
  const float scx = (float)(wl - 1) / (float)(Wh - 1);

  float fy = (float)y * scy;
  int y0 = (int)fy;
  if (y0 > hl - 1) y0 = hl - 1;
  int y1 = y0 + 1;
  if (y1 > hl - 1) y1 = hl - 1;
  float wy = fy - (float)y0;

  const size_t lrBase = (size_t)bc * hl * wl;
  const float* __restrict__ A0 = A + lrBase + (size_t)y0 * wl;
  const float* __restrict__ A1 = A + lrBase + (size_t)y1 * wl;
  const float* __restrict__ B0 = Bb + lrBase + (size_t)y0 * wl;
  const float* __restrict__ B1 = Bb + lrBase + (size_t)y1 * wl;

  const size_t hrIdx = ((size_t)bc * Hh + y) * Wh + (size_t)xq * 4;
  const float4 h4 = *(const float4*)(hr + hrIdx);
  const float hv[4] = {h4.x, h4.y, h4.z, h4.w};
  float res[4];
  const int xg = xq * 4;
#pragma unroll
  for (int j = 0; j < 4; ++j) {
    float fx = (float)(xg + j) * scx;
    int x0 = (int)fx;
    if (x0 > wl - 1) x0 = wl - 1;
    int x1 = x0 + 1;
    if (x1 > wl - 1) x1 = wl - 1;
    float wx = fx - (float)x0;
    float a0 = A0[x0] + (A0[x1] - A0[x0]) * wx;
    float a1 = A1[x0] + (A1[x1] - A1[x0]) * wx;
    float av = a0 + (a1 - a0) * wy;
    float b0 = B0[x0] + (B0[x1] - B0[x0]) * wx;
    float b1 = B1[x0] + (B1[x1] - B1[x0]) * wx;
    float bv = b0 + (b1 - b0) * wy;
    res[j] = av * hv[j] + bv;
  }
  *(float4*)(out + hrIdx) = make_float4(res[0], res[1], res[2], res[3]);
}

extern "C" void kernel_launch(void* const* d_in, const int* in_sizes, int n_in,
                              void* d_out, int out_size, void* d_ws, size_t ws_size,
                              hipStream_t stream) {
  const float* lrx = (const float*)d_in[0];
  const float* lry = (const float*)d_in[1];
  const float* hrx = (const float*)d_in[2];
  float* out = (float*)d_out;

  const int BC = 12;          // 4 batch * 3 channels
  const int hl = 512, wl = 512;
  const int Hh = 2048, Wh = 2048;

  float* A = (float*)d_ws;
  float* B = A + (size_t)BC * hl * wl;

  dim3 g1(wl / TILE, hl / TILE, BC);
  dim3 b1(TILE, TILE);
  k_ab<<<g1, b1, 0, stream>>>(lrx, lry, A, B, hl, wl);

  dim3 g2(Wh / 4 / 256, Hh, BC);
  dim3 b2(256);
  k_out<<<g2, b2, 0, stream>>>(A, B, hrx, out, hl, wl, Hh, Wh);
}

// Round 2
// 371.724 us; speedup vs baseline: 1.0376x; 1.0376x over previous
//
#include <hip/hip_runtime.h>

#define RR 8
#define TILE 32
#define EXT (TILE + 2 * RR)   // 48

// Kernel 1: per low-res pixel A = cov/(var+eps), b = mean_y - A*mean_x via
// clamped 17x17 box sums (zero-pad OOB + analytic N). Separable with
// register sliding windows to minimize LDS instruction count.
__global__ __launch_bounds__(256) void k_ab(
    const float* __restrict__ lrx, const float* __restrict__ lry,
    float* __restrict__ Aout, float* __restrict__ Bout, int H, int W) {
  __shared__ float sx[EXT][EXT];
  __shared__ float sy[EXT][EXT];
  __shared__ float hx[EXT][TILE];
  __shared__ float hy[EXT][TILE];
  __shared__ float hxy[EXT][TILE];
  __shared__ float hxx[EXT][TILE];

  const int bc = blockIdx.z;
  const size_t plane = (size_t)bc * H * W;
  const float* __restrict__ px = lrx + plane;
  const float* __restrict__ py = lry + plane;
  const int tx0 = blockIdx.x * TILE;
  const int ty0 = blockIdx.y * TILE;
  const int tid = threadIdx.y * 32 + threadIdx.x;  // block = 32x8 = 256

  // Stage 48x48 region (zero outside image bounds)
  for (int i = tid; i < EXT * EXT; i += 256) {
    int r = i / EXT, c = i % EXT;
    int gy = ty0 + r - RR, gx = tx0 + c - RR;
    float vx = 0.f, vy = 0.f;
    if (gy >= 0 && gy < H && gx >= 0 && gx < W) {
      size_t o = (size_t)gy * W + gx;
      vx = px[o];
      vy = py[o];
    }
    sx[r][c] = vx;
    sy[r][c] = vy;
  }
  __syncthreads();

  // Horizontal 17-tap sums: 48 rows x 8 groups of 4 outputs = 384 work items.
  // Each item: 5+5 ds_read_b128 (20-wide window), sliding-window 4 outputs.
  for (int q = tid; q < EXT * (TILE / 4); q += 256) {
    int r = q >> 3;
    int c0 = (q & 7) * 4;
    float xv[20], yv[20];
#pragma unroll
    for (int t = 0; t < 5; ++t) {
      float4 x4 = *(const float4*)&sx[r][c0 + 4 * t];
      float4 y4 = *(const float4*)&sy[r][c0 + 4 * t];
      xv[4 * t + 0] = x4.x; xv[4 * t + 1] = x4.y; xv[4 * t + 2] = x4.z; xv[4 * t + 3] = x4.w;
      yv[4 * t + 0] = y4.x; yv[4 * t + 1] = y4.y; yv[4 * t + 2] = y4.z; yv[4 * t + 3] = y4.w;
    }
    float pv[20], qv[20];
#pragma unroll
    for (int i = 0; i < 20; ++i) { pv[i] = xv[i] * yv[i]; qv[i] = xv[i] * xv[i]; }
    float ax = 0.f, ay = 0.f, axy = 0.f, axx = 0.f;
#pragma unroll
    for (int i = 0; i < 17; ++i) { ax += xv[i]; ay += yv[i]; axy += pv[i]; axx += qv[i]; }
    float4 ox, oy, oxy, oxx;
    ox.x = ax; oy.x = ay; oxy.x = axy; oxx.x = axx;
#pragma unroll
    for (int j = 1; j < 4; ++j) {
      ax += xv[j + 16] - xv[j - 1];
      ay += yv[j + 16] - yv[j - 1];
      axy += pv[j + 16] - pv[j - 1];
      axx += qv[j + 16] - qv[j - 1];
      (&ox.x)[j] = ax; (&oy.x)[j] = ay; (&oxy.x)[j] = axy; (&oxx.x)[j] = axx;
    }
    *(float4*)&hx[r][c0] = ox;
    *(float4*)&hy[r][c0] = oy;
    *(float4*)&hxy[r][c0] = oxy;
    *(float4*)&hxx[r][c0] = oxx;
  }
  __syncthreads();

  // Vertical 17-tap: thread (tx, ty) computes rows ty*4..ty*4+3 at col tx.
  const int c = threadIdx.x;
  const int r0 = threadIdx.y * 4;
  float vx[20], vy[20], vxy[20], vxx[20];
#pragma unroll
  for (int i = 0; i < 20; ++i) {
    vx[i] = hx[r0 + i][c];
    vy[i] = hy[r0 + i][c];
    vxy[i] = hxy[r0 + i][c];
    vxx[i] = hxx[r0 + i][c];
  }
  float sX = 0.f, sY = 0.f, sXY = 0.f, sXX = 0.f;
#pragma unroll
  for (int i = 0; i < 17; ++i) { sX += vx[i]; sY += vy[i]; sXY += vxy[i]; sXX += vxx[i]; }

  const int gx = tx0 + c;
  const int nx = min(gx + RR, W - 1) - max(gx - RR, 0) + 1;
#pragma unroll
  for (int j = 0; j < 4; ++j) {
    if (j > 0) {
      sX += vx[j + 16] - vx[j - 1];
      sY += vy[j + 16] - vy[j - 1];
      sXY += vxy[j + 16] - vxy[j - 1];
      sXX += vxx[j + 16] - vxx[j - 1];
    }
    const int gy = ty0 + r0 + j;
    const int ny = min(gy + RR, H - 1) - max(gy - RR, 0) + 1;
    float inv = 1.f / (float)(nx * ny);
    float mx = sX * inv;
    float my = sY * inv;
    float cov = sXY * inv - mx * my;
    float var = sXX * inv - mx * mx;
    float a = cov / (var + 1e-8f);
    float bv = my - a * mx;
    size_t o = plane + (size_t)gy * W + gx;
    Aout[o] = a;
    Bout[o] = bv;
  }
}

// Kernel 2: bilinear align-corners upsample of A,b fused with out = A*hr + b.
// Block = 256 threads x 4 px (1024 HR pixels of one row). y-lerp done once
// into LDS (wy uniform per row); per pixel only x-lerp from LDS.
#define KO_LDSW 264
__global__ __launch_bounds__(256) void k_out(
    const float* __restrict__ A, const float* __restrict__ Bb,
    const float* __restrict__ hr, float* __restrict__ out,
    int hl, int wl, int Hh, int Wh) {
  __shared__ float Ay[KO_LDSW];
  __shared__ float By[KO_LDSW];

  const int y = blockIdx.y;
  const int bc = blockIdx.z;
  const int xb = blockIdx.x * 1024;  // first HR pixel of this block

  const float scy = (float)(hl - 1) / (float)(Hh - 1);
  const float scx = (float)(wl - 1) / (float)(Wh - 1);

  float fy = (float)y * scy;
  int y0 = (int)fy;
  if (y0 > hl - 1) y0 = hl - 1;
  int y1 = y0 + 1;
  if (y1 > hl - 1) y1 = hl - 1;
  const float wy = fy - (float)y0;

  const int x0base = (int)((float)xb * scx);
  int x0max = (int)((float)(xb + 1023) * scx);
  const int nW = x0max - x0base + 2;  // entries [x0base .. x0max+1]

  const size_t lrBase = (size_t)bc * hl * wl;
  const float* __restrict__ A0 = A + lrBase + (size_t)y0 * wl;
  const float* __restrict__ A1 = A + lrBase + (size_t)y1 * wl;
  const float* __restrict__ B0 = Bb + lrBase + (size_t)y0 * wl;
  const float* __restrict__ B1 = Bb + lrBase + (size_t)y1 * wl;

  for (int i = threadIdx.x; i < nW; i += 256) {
    int xl = x0base + i;
    if (xl > wl - 1) xl = wl - 1;
    float a0 = A0[xl], a1 = A1[xl];
    float b0 = B0[xl], b1 = B1[xl];
    Ay[i] = a0 + (a1 - a0) * wy;
    By[i] = b0 + (b1 - b0) * wy;
  }
  __syncthreads();

  const int xg = xb + threadIdx.x * 4;
  const size_t hrIdx = ((size_t)bc * Hh + y) * Wh + xg;
  const float4 h4 = *(const float4*)(hr + hrIdx);
  const float hv[4] = {h4.x, h4.y, h4.z, h4.w};
  float res[4];
#pragma unroll
  for (int j = 0; j < 4; ++j) {
    float fx = (float)(xg + j) * scx;
    int x0 = (int)fx;
    float wx = fx - (float)x0;
    int li = x0 - x0base;
    float a = Ay[li] + (Ay[li + 1] - Ay[li]) * wx;
    float b = By[li] + (By[li + 1] - By[li]) * wx;
    res[j] = a * hv[j] + b;
  }
  *(float4*)(out + hrIdx) = make_float4(res[0], res[1], res[2], res[3]);
}

extern "C" void kernel_launch(void* const* d_in, const int* in_sizes, int n_in,
                              void* d_out, int out_size, void* d_ws, size_t ws_size,
                              hipStream_t stream) {
  const float* lrx = (const float*)d_in[0];
  const float* lry = (const float*)d_in[1];
  const float* hrx = (const float*)d_in[2];
  float* out = (float*)d_out;

  const int BC = 12;  // 4 batch * 3 channels
  const int hl = 512, wl = 512;
  const int Hh = 2048, Wh = 2048;

  float* A = (float*)d_ws;
  float* B = A + (size_t)BC * hl * wl;

  dim3 g1(wl / TILE, hl / TILE, BC);
  dim3 b1(32, 8);
  k_ab<<<g1, b1, 0, stream>>>(lrx, lry, A, B, hl, wl);

  dim3 g2(Wh / 1024, Hh, BC);
  dim3 b2(256);
  k_out<<<g2, b2, 0, stream>>>(A, B, hrx, out, hl, wl, Hh, Wh);
}